// Round 9
// baseline (145.295 us; speedup 1.0000x reference)
//
#include <hip/hip_runtime.h>

typedef __attribute__((ext_vector_type(8))) short short8;       // 8 x bf16 (4 VGPR)
typedef __attribute__((ext_vector_type(4))) float f32x4;         // MFMA acc
typedef __attribute__((ext_vector_type(4))) unsigned int u32x4;

constexpr int HID = 32;
constexpr int LAT = 64;    // latent dim
constexpr int EPW = 64;    // edges per wave-block (4 tiles x 16 edges)
constexpr int NFRAG  = 12; // W1aug^T [128 x 48]: 4 k-steps x 3 N-tiles
constexpr int NFRAG2 = 2;  // W2aug^T [32 x 32]: 2 tiles, sigma' k-order
constexpr int NFRAG3 = 1;  // W3aug^T [32 x 16]: rows(c)<4 real

// ---------- helpers ----------
__device__ __forceinline__ unsigned pk2(float lo, float hi) {
    unsigned r;
    asm("v_cvt_pk_bf16_f32 %0, %1, %2" : "=v"(r) : "v"(lo), "v"(hi));
    return r;
}
// packed-bf16-pair min/max (inputs exact bf16 -> cvt_pk repack is exact)
__device__ __forceinline__ void mnmx_word(unsigned a, unsigned b, unsigned& mn, unsigned& mx) {
    float al = __uint_as_float(a << 16), ah = __uint_as_float(a & 0xFFFF0000u);
    float bl = __uint_as_float(b << 16), bh = __uint_as_float(b & 0xFFFF0000u);
    mn = pk2(fminf(al, bl), fminf(ah, bh));
    mx = pk2(fmaxf(al, bl), fmaxf(ah, bh));
}
struct MnMx4 { unsigned w0, w1, x0, x1; };
__device__ __forceinline__ MnMx4 mnmx4(float4 a, float4 b) {
    MnMx4 r;
    r.w0 = pk2(fminf(a.x, b.x), fminf(a.y, b.y));
    r.w1 = pk2(fminf(a.z, b.z), fminf(a.w, b.w));
    r.x0 = pk2(fmaxf(a.x, b.x), fmaxf(a.y, b.y));
    r.x1 = pk2(fmaxf(a.z, b.z), fmaxf(a.w, b.w));
    return r;
}

// ---------- merged prep: build frags (blocks 0-3) + x fp32->bf16 (blocks 4+) ----------
__global__ __launch_bounds__(256) void prep_kernel(const float* __restrict__ x,
                                                   const float* __restrict__ W1,
                                                   const float* __restrict__ Wd,
                                                   const float* __restrict__ W2,
                                                   const float* __restrict__ W3,
                                                   unsigned short* __restrict__ fr,
                                                   unsigned short* __restrict__ fr2,
                                                   unsigned short* __restrict__ fr3,
                                                   unsigned short* __restrict__ xb, int n8) {
    if (blockIdx.x < 4) {
        int id = blockIdx.x * 256 + threadIdx.x;
        if (id < NFRAG * 64) {
            int l = id & 63;
            int ft = id >> 6;
            int s = ft / 3, t = ft - s * 3;
            int g = l >> 4, c = l & 15;
            unsigned w[4];
            #pragma unroll
            for (int q = 0; q < 4; ++q) {
                int k = s * 32 + g * 8 + q * 2;
                float lo, hi;
                if (t < 2) { lo = W1[k * HID + t * 16 + c]; hi = W1[(k + 1) * HID + t * 16 + c]; }
                else { lo = (c < 4) ? Wd[k * 4 + c] : 0.0f; hi = (c < 4) ? Wd[(k + 1) * 4 + c] : 0.0f; }
                w[q] = pk2(lo, hi);
            }
            u32x4 v = { w[0], w[1], w[2], w[3] };
            ((u32x4*)fr)[ft * 64 + l] = v;
        } else if (id < (NFRAG + NFRAG2) * 64) {
            int f2 = id - NFRAG * 64;
            int l = f2 & 63;
            int t = f2 >> 6;
            int g = l >> 4, c = l & 15;
            int col = t * 16 + c;
            unsigned w[4];
            #pragma unroll
            for (int q = 0; q < 4; ++q) {
                int kb = (q < 2) ? (g * 4 + 2 * q) : (16 + g * 4 + 2 * (q - 2));
                float lo = W2[kb * HID + col] + (kb == col ? 1.0f : 0.0f);
                float hi = W2[(kb + 1) * HID + col] + ((kb + 1) == col ? 1.0f : 0.0f);
                w[q] = pk2(lo, hi);
            }
            u32x4 v = { w[0], w[1], w[2], w[3] };
            ((u32x4*)fr2)[t * 64 + l] = v;
        } else if (id < (NFRAG + NFRAG2 + NFRAG3) * 64) {
            int l = id - (NFRAG + NFRAG2) * 64;
            int g = l >> 4, c = l & 15;
            unsigned w[4];
            #pragma unroll
            for (int q = 0; q < 4; ++q) {
                int kb = (q < 2) ? (g * 4 + 2 * q) : (16 + g * 4 + 2 * (q - 2));
                float lo = (c < 4) ? W3[kb * 4 + c] : 0.0f;
                float hi = (c < 4) ? W3[(kb + 1) * 4 + c] : 0.0f;
                w[q] = pk2(lo, hi);
            }
            u32x4 v = { w[0], w[1], w[2], w[3] };
            ((u32x4*)fr3)[l] = v;
        }
    } else {
        int i = (blockIdx.x - 4) * 256 + threadIdx.x;
        if (i < n8) {
            const float4* p = (const float4*)x + (long)i * 2;
            float4 a = p[0], b = p[1];
            u32x4 v = { pk2(a.x, a.y), pk2(a.z, a.w), pk2(b.x, b.y), pk2(b.z, b.w) };
            ((u32x4*)xb)[i] = v;
        }
    }
}

// ---------- main kernel: 1-wave blocks; weights-as-A, edges-as-B ----------
template<int XMODE>
__global__ __launch_bounds__(64, 4) void edge_mfma_kernel(
    const float* __restrict__ xf,
    const unsigned short* __restrict__ xb,
    const unsigned short* __restrict__ fr,
    const unsigned short* __restrict__ fr2,
    const unsigned short* __restrict__ fr3,
    const int* __restrict__ ei,
    const float* __restrict__ b1, const float* __restrict__ bd,
    const float* __restrict__ b2, const float* __restrict__ b3,
    float* __restrict__ out, int E)
{
    const int l = threadIdx.x & 63;
    const int g = l >> 4, r = l & 15;
    const long waveBase = (long)blockIdx.x * EPW;

    // 1) Edge indices first (oldest vmem)
    int sidx[4], tidx[4];
    #pragma unroll
    for (int t = 0; t < 4; ++t) {
        long e = waveBase + t * 16 + r;
        long ecl = (e < E) ? e : (long)(E - 1);
        sidx[t] = ei[ecl];
        tidx[t] = ei[(long)E + ecl];
    }

    // 2) Weight A-fragments (L2-hot after first blocks)
    short8 bfr[NFRAG];
    #pragma unroll
    for (int f = 0; f < NFRAG; ++f) bfr[f] = ((const short8*)fr)[f * 64 + l];
    short8 w2t[NFRAG2];
    #pragma unroll
    for (int f = 0; f < NFRAG2; ++f) w2t[f] = ((const short8*)fr2)[f * 64 + l];
    short8 w3t = ((const short8*)fr3)[l];

    // Biases for the out-feats this lane holds (rows 4g+p and 16+4g+p)
    const float4 b1a = ((const float4*)b1)[g], b1b = ((const float4*)b1)[4 + g];
    const float4 b2a = ((const float4*)b2)[g], b2b = ((const float4*)b2)[4 + g];
    // C-init for the direct-path mfma: channels live at local rows 0-3 (g==0)
    f32x4 a2init;
    #pragma unroll
    for (int p = 0; p < 4; ++p) a2init[p] = (g == 0) ? (bd[p] + b3[p]) : 0.0f;

    // af* are B-fragments (lane holds edge r's x_cat k-slots)
    auto compute_tile = [&](short8 af0, short8 af1, short8 af2, short8 af3, long estore) {
        f32x4 a0 = {0.f, 0.f, 0.f, 0.f}, a1 = a0;
        f32x4 a2 = a2init;
        a0 = __builtin_amdgcn_mfma_f32_16x16x32_bf16(bfr[0],  af0, a0, 0, 0, 0);
        a1 = __builtin_amdgcn_mfma_f32_16x16x32_bf16(bfr[1],  af0, a1, 0, 0, 0);
        a2 = __builtin_amdgcn_mfma_f32_16x16x32_bf16(bfr[2],  af0, a2, 0, 0, 0);
        a0 = __builtin_amdgcn_mfma_f32_16x16x32_bf16(bfr[3],  af1, a0, 0, 0, 0);
        a1 = __builtin_amdgcn_mfma_f32_16x16x32_bf16(bfr[4],  af1, a1, 0, 0, 0);
        a2 = __builtin_amdgcn_mfma_f32_16x16x32_bf16(bfr[5],  af1, a2, 0, 0, 0);
        a0 = __builtin_amdgcn_mfma_f32_16x16x32_bf16(bfr[6],  af2, a0, 0, 0, 0);
        a1 = __builtin_amdgcn_mfma_f32_16x16x32_bf16(bfr[7],  af2, a1, 0, 0, 0);
        a2 = __builtin_amdgcn_mfma_f32_16x16x32_bf16(bfr[8],  af2, a2, 0, 0, 0);
        a0 = __builtin_amdgcn_mfma_f32_16x16x32_bf16(bfr[9],  af3, a0, 0, 0, 0);
        a1 = __builtin_amdgcn_mfma_f32_16x16x32_bf16(bfr[10], af3, a1, 0, 0, 0);
        a2 = __builtin_amdgcn_mfma_f32_16x16x32_bf16(bfr[11], af3, a2, 0, 0, 0);

        // h1 = relu(. + b1): lane already holds the next layer's B-fragment slots
        union { short8 s; u32x4 u; } hf;
        hf.u[0] = pk2(fmaxf(a0[0] + b1a.x, 0.0f), fmaxf(a0[1] + b1a.y, 0.0f));
        hf.u[1] = pk2(fmaxf(a0[2] + b1a.z, 0.0f), fmaxf(a0[3] + b1a.w, 0.0f));
        hf.u[2] = pk2(fmaxf(a1[0] + b1b.x, 0.0f), fmaxf(a1[1] + b1b.y, 0.0f));
        hf.u[3] = pk2(fmaxf(a1[2] + b1b.z, 0.0f), fmaxf(a1[3] + b1b.w, 0.0f));

        f32x4 d0 = {0.f, 0.f, 0.f, 0.f}, d1 = d0;
        d0 = __builtin_amdgcn_mfma_f32_16x16x32_bf16(w2t[0], hf.s, d0, 0, 0, 0);
        d1 = __builtin_amdgcn_mfma_f32_16x16x32_bf16(w2t[1], hf.s, d1, 0, 0, 0);

        union { short8 s; u32x4 u; } hf2;
        hf2.u[0] = pk2(fmaxf(d0[0] + b2a.x, 0.0f), fmaxf(d0[1] + b2a.y, 0.0f));
        hf2.u[1] = pk2(fmaxf(d0[2] + b2a.z, 0.0f), fmaxf(d0[3] + b2a.w, 0.0f));
        hf2.u[2] = pk2(fmaxf(d1[0] + b2b.x, 0.0f), fmaxf(d1[1] + b2b.y, 0.0f));
        hf2.u[3] = pk2(fmaxf(d1[2] + b2b.z, 0.0f), fmaxf(d1[3] + b2b.w, 0.0f));

        // MFMA3: rows 0-3 = channels (lanes g==0), C carries direct path + biases
        f32x4 d3 = __builtin_amdgcn_mfma_f32_16x16x32_bf16(w3t, hf2.s, a2, 0, 0, 0);

        if (g == 0 && estore < E)
            ((float4*)out)[estore] = make_float4(d3[0], d3[1], d3[2], d3[3]);
    };

    if (XMODE == 1) {
        u32x4 Asl, Ash, Atl, Ath, Bsl, Bsh, Btl, Bth;
        u32x4 Csl, Csh, Ctl, Cth, Dsl, Dsh, Dtl, Dth;
        #define GATHER(P, t) { \
            const u32x4* ps = (const u32x4*)(xb + (long)sidx[t] * LAT); \
            const u32x4* pt = (const u32x4*)(xb + (long)tidx[t] * LAT); \
            P##sl = ps[g]; P##sh = ps[4 + g]; P##tl = pt[g]; P##th = pt[4 + g]; }
        #define COMPUTE(P, t) { \
            union { short8 s; u32x4 u; } af0, af1, af2, af3; \
            _Pragma("unroll") \
            for (int q = 0; q < 4; ++q) { \
                unsigned mn, mx; \
                mnmx_word(P##sl[q], P##tl[q], mn, mx); af0.u[q] = mn; af2.u[q] = mx; \
                mnmx_word(P##sh[q], P##th[q], mn, mx); af1.u[q] = mn; af3.u[q] = mx; \
            } \
            compute_tile(af0.s, af1.s, af2.s, af3.s, waveBase + (t) * 16 + r); }

        GATHER(A, 0)
        GATHER(B, 1)
        GATHER(C, 2)
        GATHER(D, 3)
        COMPUTE(A, 0)
        COMPUTE(B, 1)
        COMPUTE(C, 2)
        COMPUTE(D, 3)
        #undef GATHER
        #undef COMPUTE
    } else {
        #pragma unroll
        for (int t = 0; t < 4; ++t) {
            const float4* ps = (const float4*)(xf + (long)sidx[t] * LAT);
            const float4* pt = (const float4*)(xf + (long)tidx[t] * LAT);
            float4 sa = ps[2 * g], sb = ps[2 * g + 1], sc = ps[8 + 2 * g], sd = ps[9 + 2 * g];
            float4 ta = pt[2 * g], tb = pt[2 * g + 1], tc = pt[8 + 2 * g], td = pt[9 + 2 * g];
            MnMx4 m0 = mnmx4(sa, ta);
            MnMx4 m1 = mnmx4(sb, tb);
            MnMx4 m2 = mnmx4(sc, tc);
            MnMx4 m3 = mnmx4(sd, td);
            union { short8 s; u32x4 u; } af0, af1, af2, af3;
            af0.u[0] = m0.w0; af0.u[1] = m0.w1; af2.u[0] = m0.x0; af2.u[1] = m0.x1;
            af0.u[2] = m1.w0; af0.u[3] = m1.w1; af2.u[2] = m1.x0; af2.u[3] = m1.x1;
            af1.u[0] = m2.w0; af1.u[1] = m2.w1; af3.u[0] = m2.x0; af3.u[1] = m2.x1;
            af1.u[2] = m3.w0; af1.u[3] = m3.w1; af3.u[2] = m3.x0; af3.u[3] = m3.x1;
            compute_tile(af0.s, af1.s, af2.s, af3.s, waveBase + t * 16 + r);
        }
    }
}

// ---------- fallback (tiny ws): per-thread fp32 kernel ----------
__global__ __launch_bounds__(256) void edge_pred_fp32_kernel(
    const float* __restrict__ x, const int* __restrict__ ei,
    const float* __restrict__ Wd, const float* __restrict__ bd,
    const float* __restrict__ W1, const float* __restrict__ b1,
    const float* __restrict__ W2, const float* __restrict__ b2,
    const float* __restrict__ W3, const float* __restrict__ b3,
    float* __restrict__ out, int E)
{
    int e = blockIdx.x * blockDim.x + threadIdx.x;
    if (e >= E) return;
    int s = ei[e];
    int t = ei[E + e];
    const float4* xs4 = (const float4*)(x + (long)s * 64);
    const float4* xt4 = (const float4*)(x + (long)t * 64);
    float h[HID];
    #pragma unroll
    for (int j = 0; j < HID; ++j) h[j] = b1[j];
    float d0 = bd[0], d1 = bd[1], d2 = bd[2], d3 = bd[3];
    #pragma unroll 2
    for (int c = 0; c < 16; ++c) {
        float4 a = xs4[c];
        float4 b = xt4[c];
        float mn[4] = {fminf(a.x,b.x), fminf(a.y,b.y), fminf(a.z,b.z), fminf(a.w,b.w)};
        float mx[4] = {fmaxf(a.x,b.x), fmaxf(a.y,b.y), fmaxf(a.z,b.z), fmaxf(a.w,b.w)};
        #pragma unroll
        for (int q = 0; q < 4; ++q) {
            int lidx = c * 4 + q;
            const float* wlo = W1 + lidx * HID;
            const float* whi = W1 + (64 + lidx) * HID;
            #pragma unroll
            for (int j = 0; j < HID; ++j) { h[j] += mn[q]*wlo[j]; h[j] += mx[q]*whi[j]; }
            const float* dlo = Wd + lidx * 4;
            const float* dhi = Wd + (64 + lidx) * 4;
            d0 += mn[q]*dlo[0] + mx[q]*dhi[0];
            d1 += mn[q]*dlo[1] + mx[q]*dhi[1];
            d2 += mn[q]*dlo[2] + mx[q]*dhi[2];
            d3 += mn[q]*dlo[3] + mx[q]*dhi[3];
        }
    }
    float h1[HID];
    #pragma unroll
    for (int j = 0; j < HID; ++j) h1[j] = fmaxf(h[j], 0.0f);
    float s2[HID];
    #pragma unroll
    for (int j = 0; j < HID; ++j) s2[j] = b2[j] + h1[j];
    #pragma unroll 4
    for (int k = 0; k < HID; ++k) {
        const float* w2r = W2 + k * HID;
        #pragma unroll
        for (int j = 0; j < HID; ++j) s2[j] += h1[k] * w2r[j];
    }
    float o0 = b3[0] + d0, o1 = b3[1] + d1, o2 = b3[2] + d2, o3 = b3[3] + d3;
    #pragma unroll
    for (int k = 0; k < HID; ++k) {
        float hk = fmaxf(s2[k], 0.0f);
        const float* w3r = W3 + k * 4;
        o0 += hk*w3r[0]; o1 += hk*w3r[1]; o2 += hk*w3r[2]; o3 += hk*w3r[3];
    }
    *(float4*)(out + (long)e * 4) = make_float4(o0, o1, o2, o3);
}

extern "C" void kernel_launch(void* const* d_in, const int* in_sizes, int n_in,
                              void* d_out, int out_size, void* d_ws, size_t ws_size,
                              hipStream_t stream) {
    const float* x  = (const float*)d_in[0];
    const int*   ei = (const int*)d_in[1];
    const float* Wd = (const float*)d_in[2];
    const float* bd = (const float*)d_in[3];
    const float* W1 = (const float*)d_in[4];
    const float* b1 = (const float*)d_in[5];
    const float* W2 = (const float*)d_in[6];
    const float* b2 = (const float*)d_in[7];
    const float* W3 = (const float*)d_in[8];
    const float* b3 = (const float*)d_in[9];
    float* out = (float*)d_out;

    int E  = in_sizes[1] / 2;
    int NN = in_sizes[0] / LAT;

    size_t fbytes  = (size_t)NFRAG  * 64 * 16;   // 12 KB W1aug frags
    size_t f2bytes = (size_t)NFRAG2 * 64 * 16;   // 2 KB  W2aug frags
    size_t f3bytes = (size_t)NFRAG3 * 64 * 16;   // 1 KB  W3aug frag
    size_t fall    = fbytes + f2bytes + f3bytes;
    size_t fpad    = (fall + 255) & ~(size_t)255;
    size_t xbytes  = (size_t)NN * LAT * 2;       // bf16 x

    int grid = (E + EPW - 1) / EPW;              // 1-wave blocks
    if (ws_size >= fpad + xbytes) {
        unsigned short* frg  = (unsigned short*)d_ws;
        unsigned short* frg2 = (unsigned short*)((char*)d_ws + fbytes);
        unsigned short* frg3 = (unsigned short*)((char*)d_ws + fbytes + f2bytes);
        unsigned short* xb   = (unsigned short*)((char*)d_ws + fpad);
        int n8 = NN * LAT / 8;
        int prep_grid = 4 + (n8 + 255) / 256;
        hipLaunchKernelGGL(prep_kernel, dim3(prep_grid), dim3(256), 0, stream,
                           x, W1, Wd, W2, W3, frg, frg2, frg3, xb, n8);
        hipLaunchKernelGGL((edge_mfma_kernel<1>), dim3(grid), dim3(64), 0, stream,
                           x, xb, frg, frg2, frg3, ei, b1, bd, b2, b3, out, E);
    } else if (ws_size >= fall) {
        unsigned short* frg  = (unsigned short*)d_ws;
        unsigned short* frg2 = (unsigned short*)((char*)d_ws + fbytes);
        unsigned short* frg3 = (unsigned short*)((char*)d_ws + fbytes + f2bytes);
        hipLaunchKernelGGL(prep_kernel, dim3(4), dim3(256), 0, stream,
                           x, W1, Wd, W2, W3, frg, frg2, frg3,
                           (unsigned short*)nullptr, 0);
        hipLaunchKernelGGL((edge_mfma_kernel<0>), dim3(grid), dim3(64), 0, stream,
                           x, (const unsigned short*)nullptr, frg, frg2, frg3,
                           ei, b1, bd, b2, b3, out, E);
    } else {
        hipLaunchKernelGGL(edge_pred_fp32_kernel, dim3((E + 255) / 256), dim3(256), 0, stream,
                           x, ei, Wd, bd, W1, b1, W2, b2, W3, b3, out, E);
    }
}

// Round 10
// 67.969 us; speedup vs baseline: 2.1376x; 2.1376x over previous
//
#include <hip/hip_runtime.h>

typedef __attribute__((ext_vector_type(8))) short short8;       // 8 x bf16 (4 VGPR)
typedef __attribute__((ext_vector_type(4))) float f32x4;         // MFMA acc
typedef __attribute__((ext_vector_type(4))) unsigned int u32x4;

constexpr int HID = 32;
constexpr int LAT = 64;    // latent dim
constexpr int EPB = 256;   // edges per chunk (4 waves x 4 tiles x 16 edges)
constexpr int NFRAG  = 12; // W1aug^T [128 x 48]: 4 k-steps x 3 N-tiles
constexpr int NFRAG2 = 2;  // W2aug^T [32 x 32]
constexpr int NFRAG3 = 1;  // W3aug^T [32 x 16]
constexpr int NWE = (NFRAG + NFRAG2 + NFRAG3) * 64;  // 960 u32x4 weight entries

// ---------- helpers ----------
__device__ __forceinline__ unsigned pk2(float lo, float hi) {
    unsigned r;
    asm("v_cvt_pk_bf16_f32 %0, %1, %2" : "=v"(r) : "v"(lo), "v"(hi));
    return r;
}
__device__ __forceinline__ void mnmx_word(unsigned a, unsigned b, unsigned& mn, unsigned& mx) {
    float al = __uint_as_float(a << 16), ah = __uint_as_float(a & 0xFFFF0000u);
    float bl = __uint_as_float(b << 16), bh = __uint_as_float(b & 0xFFFF0000u);
    mn = pk2(fminf(al, bl), fminf(ah, bh));
    mx = pk2(fmaxf(al, bl), fmaxf(ah, bh));
}
struct MnMx4 { unsigned w0, w1, x0, x1; };
__device__ __forceinline__ MnMx4 mnmx4(float4 a, float4 b) {
    MnMx4 r;
    r.w0 = pk2(fminf(a.x, b.x), fminf(a.y, b.y));
    r.w1 = pk2(fminf(a.z, b.z), fminf(a.w, b.w));
    r.x0 = pk2(fmaxf(a.x, b.x), fmaxf(a.y, b.y));
    r.x1 = pk2(fmaxf(a.z, b.z), fmaxf(a.w, b.w));
    return r;
}

// ---------- merged prep: build frags (blocks 0-3) + x fp32->bf16 (blocks 4+) ----------
__global__ __launch_bounds__(256) void prep_kernel(const float* __restrict__ x,
                                                   const float* __restrict__ W1,
                                                   const float* __restrict__ Wd,
                                                   const float* __restrict__ W2,
                                                   const float* __restrict__ W3,
                                                   unsigned short* __restrict__ fr,
                                                   unsigned short* __restrict__ fr2,
                                                   unsigned short* __restrict__ fr3,
                                                   unsigned short* __restrict__ xb, int n8) {
    if (blockIdx.x < 4) {
        int id = blockIdx.x * 256 + threadIdx.x;
        if (id < NFRAG * 64) {
            int l = id & 63;
            int ft = id >> 6;
            int s = ft / 3, t = ft - s * 3;
            int g = l >> 4, c = l & 15;
            unsigned w[4];
            #pragma unroll
            for (int q = 0; q < 4; ++q) {
                int k = s * 32 + g * 8 + q * 2;
                float lo, hi;
                if (t < 2) { lo = W1[k * HID + t * 16 + c]; hi = W1[(k + 1) * HID + t * 16 + c]; }
                else { lo = (c < 4) ? Wd[k * 4 + c] : 0.0f; hi = (c < 4) ? Wd[(k + 1) * 4 + c] : 0.0f; }
                w[q] = pk2(lo, hi);
            }
            u32x4 v = { w[0], w[1], w[2], w[3] };
            ((u32x4*)fr)[ft * 64 + l] = v;
        } else if (id < (NFRAG + NFRAG2) * 64) {
            int f2 = id - NFRAG * 64;
            int l = f2 & 63;
            int t = f2 >> 6;
            int g = l >> 4, c = l & 15;
            int col = t * 16 + c;
            unsigned w[4];
            #pragma unroll
            for (int q = 0; q < 4; ++q) {
                int kb = (q < 2) ? (g * 4 + 2 * q) : (16 + g * 4 + 2 * (q - 2));
                float lo = W2[kb * HID + col] + (kb == col ? 1.0f : 0.0f);
                float hi = W2[(kb + 1) * HID + col] + ((kb + 1) == col ? 1.0f : 0.0f);
                w[q] = pk2(lo, hi);
            }
            u32x4 v = { w[0], w[1], w[2], w[3] };
            ((u32x4*)fr2)[t * 64 + l] = v;
        } else if (id < (NFRAG + NFRAG2 + NFRAG3) * 64) {
            int l = id - (NFRAG + NFRAG2) * 64;
            int g = l >> 4, c = l & 15;
            unsigned w[4];
            #pragma unroll
            for (int q = 0; q < 4; ++q) {
                int kb = (q < 2) ? (g * 4 + 2 * q) : (16 + g * 4 + 2 * (q - 2));
                float lo = (c < 4) ? W3[kb * 4 + c] : 0.0f;
                float hi = (c < 4) ? W3[(kb + 1) * 4 + c] : 0.0f;
                w[q] = pk2(lo, hi);
            }
            u32x4 v = { w[0], w[1], w[2], w[3] };
            ((u32x4*)fr3)[l] = v;
        }
    } else {
        int i = (blockIdx.x - 4) * 256 + threadIdx.x;
        if (i < n8) {
            const float4* p = (const float4*)x + (long)i * 2;
            float4 a = p[0], b = p[1];
            u32x4 v = { pk2(a.x, a.y), pk2(a.z, a.w), pk2(b.x, b.y), pk2(b.z, b.w) };
            ((u32x4*)xb)[i] = v;
        }
    }
}

// ---------- main kernel: persistent, weights in LDS, 2-deep gather rotation ----------
template<int XMODE>
__global__ __launch_bounds__(256, 4) void edge_mfma_kernel(
    const float* __restrict__ xf,
    const unsigned short* __restrict__ xb,
    const unsigned short* __restrict__ fr,   // contiguous fr|fr2|fr3 (960 u32x4)
    const int* __restrict__ ei,
    const float* __restrict__ b1, const float* __restrict__ bd,
    const float* __restrict__ b2, const float* __restrict__ b3,
    float* __restrict__ out, int E, int nch)
{
    __shared__ u32x4 wlds[NWE];          // 15.3 KB weight fragments
    __shared__ float b1l[32], b2l[32], db3l[4];
    const int tid = threadIdx.x;
    for (int i = tid; i < NWE; i += 256) wlds[i] = ((const u32x4*)fr)[i];
    if (tid < 32) { b1l[tid] = b1[tid]; b2l[tid] = b2[tid]; }
    else if (tid < 36) db3l[tid - 32] = bd[tid - 32] + b3[tid - 32];
    __syncthreads();
    if ((int)blockIdx.x >= nch) return;   // uniform per block, after barrier

    const int l = tid & 63;
    const int wv = tid >> 6;
    const int g = l >> 4, r = l & 15;
    const short8* __restrict__ wl = (const short8*)wlds;

    // af* are B-fragments (lane holds edge r's x_cat k-slots)
    auto mfma_core = [&](short8 af0, short8 af1, short8 af2, short8 af3, long estore) {
        // per-tile bias / direct-path C-init from LDS (keeps VGPR pressure low)
        const float4 b1a = ((const float4*)b1l)[g], b1b = ((const float4*)b1l)[4 + g];
        const float4 b2a = ((const float4*)b2l)[g], b2b = ((const float4*)b2l)[4 + g];
        const float4 dv = *(const float4*)db3l;
        f32x4 a2;
        a2[0] = (g == 0) ? dv.x : 0.f;
        a2[1] = (g == 0) ? dv.y : 0.f;
        a2[2] = (g == 0) ? dv.z : 0.f;
        a2[3] = (g == 0) ? dv.w : 0.f;
        f32x4 a0 = {0.f, 0.f, 0.f, 0.f}, a1 = a0;
        a0 = __builtin_amdgcn_mfma_f32_16x16x32_bf16(wl[0 * 64 + l],  af0, a0, 0, 0, 0);
        a1 = __builtin_amdgcn_mfma_f32_16x16x32_bf16(wl[1 * 64 + l],  af0, a1, 0, 0, 0);
        a2 = __builtin_amdgcn_mfma_f32_16x16x32_bf16(wl[2 * 64 + l],  af0, a2, 0, 0, 0);
        a0 = __builtin_amdgcn_mfma_f32_16x16x32_bf16(wl[3 * 64 + l],  af1, a0, 0, 0, 0);
        a1 = __builtin_amdgcn_mfma_f32_16x16x32_bf16(wl[4 * 64 + l],  af1, a1, 0, 0, 0);
        a2 = __builtin_amdgcn_mfma_f32_16x16x32_bf16(wl[5 * 64 + l],  af1, a2, 0, 0, 0);
        a0 = __builtin_amdgcn_mfma_f32_16x16x32_bf16(wl[6 * 64 + l],  af2, a0, 0, 0, 0);
        a1 = __builtin_amdgcn_mfma_f32_16x16x32_bf16(wl[7 * 64 + l],  af2, a1, 0, 0, 0);
        a2 = __builtin_amdgcn_mfma_f32_16x16x32_bf16(wl[8 * 64 + l],  af2, a2, 0, 0, 0);
        a0 = __builtin_amdgcn_mfma_f32_16x16x32_bf16(wl[9 * 64 + l],  af3, a0, 0, 0, 0);
        a1 = __builtin_amdgcn_mfma_f32_16x16x32_bf16(wl[10 * 64 + l], af3, a1, 0, 0, 0);
        a2 = __builtin_amdgcn_mfma_f32_16x16x32_bf16(wl[11 * 64 + l], af3, a2, 0, 0, 0);

        // h1 = relu(. + b1): lane already holds the next layer's B-fragment slots
        union { short8 s; u32x4 u; } hf;
        hf.u[0] = pk2(fmaxf(a0[0] + b1a.x, 0.0f), fmaxf(a0[1] + b1a.y, 0.0f));
        hf.u[1] = pk2(fmaxf(a0[2] + b1a.z, 0.0f), fmaxf(a0[3] + b1a.w, 0.0f));
        hf.u[2] = pk2(fmaxf(a1[0] + b1b.x, 0.0f), fmaxf(a1[1] + b1b.y, 0.0f));
        hf.u[3] = pk2(fmaxf(a1[2] + b1b.z, 0.0f), fmaxf(a1[3] + b1b.w, 0.0f));

        f32x4 d0 = {0.f, 0.f, 0.f, 0.f}, d1 = d0;
        d0 = __builtin_amdgcn_mfma_f32_16x16x32_bf16(wl[12 * 64 + l], hf.s, d0, 0, 0, 0);
        d1 = __builtin_amdgcn_mfma_f32_16x16x32_bf16(wl[13 * 64 + l], hf.s, d1, 0, 0, 0);

        union { short8 s; u32x4 u; } hf2;
        hf2.u[0] = pk2(fmaxf(d0[0] + b2a.x, 0.0f), fmaxf(d0[1] + b2a.y, 0.0f));
        hf2.u[1] = pk2(fmaxf(d0[2] + b2a.z, 0.0f), fmaxf(d0[3] + b2a.w, 0.0f));
        hf2.u[2] = pk2(fmaxf(d1[0] + b2b.x, 0.0f), fmaxf(d1[1] + b2b.y, 0.0f));
        hf2.u[3] = pk2(fmaxf(d1[2] + b2b.z, 0.0f), fmaxf(d1[3] + b2b.w, 0.0f));

        // MFMA3: rows 0-3 = channels (g==0 lanes), C carries direct path + biases
        f32x4 d3 = __builtin_amdgcn_mfma_f32_16x16x32_bf16(wl[14 * 64 + l], hf2.s, a2, 0, 0, 0);

        if (g == 0 && estore < E)
            ((float4*)out)[estore] = make_float4(d3[0], d3[1], d3[2], d3[3]);
    };

    int sidx[4], tidx[4], nsidx[4], ntidx[4];
    auto load_idx = [&](int c, int* si, int* ti) {
        long base = (long)c * EPB + wv * 64;
        #pragma unroll
        for (int t = 0; t < 4; ++t) {
            long e = base + t * 16 + r;
            long ecl = (e < E) ? e : (long)(E - 1);
            si[t] = ei[ecl];
            ti[t] = ei[(long)E + ecl];
        }
    };

    if (XMODE == 1) {
        int c = blockIdx.x;
        u32x4 Asl, Ash, Atl, Ath, Bsl, Bsh, Btl, Bth;
        #define GATHER(P, si, ti) { \
            const u32x4* ps = (const u32x4*)(xb + (long)(si) * LAT); \
            const u32x4* pt = (const u32x4*)(xb + (long)(ti) * LAT); \
            P##sl = ps[g]; P##sh = ps[4 + g]; P##tl = pt[g]; P##th = pt[4 + g]; }
        #define COMPUTE(P, estore) { \
            union { short8 s; u32x4 u; } af0, af1, af2, af3; \
            _Pragma("unroll") \
            for (int q = 0; q < 4; ++q) { \
                unsigned mn, mx; \
                mnmx_word(P##sl[q], P##tl[q], mn, mx); af0.u[q] = mn; af2.u[q] = mx; \
                mnmx_word(P##sh[q], P##th[q], mn, mx); af1.u[q] = mn; af3.u[q] = mx; \
            } \
            mfma_core(af0.s, af1.s, af2.s, af3.s, (estore)); }

        load_idx(c, sidx, tidx);
        GATHER(A, sidx[0], tidx[0])
        GATHER(B, sidx[1], tidx[1])
        for (;;) {
            const long ebase = (long)c * EPB + wv * 64;
            const int cn = c + (int)gridDim.x;
            const bool more = (cn < nch);
            if (more) load_idx(cn, nsidx, ntidx);       // idx prefetch, covered by computes
            COMPUTE(A, ebase + 0 * 16 + r)
            GATHER(A, sidx[2], tidx[2])
            COMPUTE(B, ebase + 1 * 16 + r)
            GATHER(B, sidx[3], tidx[3])
            COMPUTE(A, ebase + 2 * 16 + r)
            if (more) GATHER(A, nsidx[0], ntidx[0])     // next chunk's fill overlaps
            COMPUTE(B, ebase + 3 * 16 + r)
            if (!more) break;
            GATHER(B, nsidx[1], ntidx[1])
            #pragma unroll
            for (int t = 0; t < 4; ++t) { sidx[t] = nsidx[t]; tidx[t] = ntidx[t]; }
            c = cn;
        }
        #undef GATHER
        #undef COMPUTE
    } else {
        for (int c = blockIdx.x; c < nch; c += gridDim.x) {
            const long ebase = (long)c * EPB + wv * 64;
            load_idx(c, sidx, tidx);
            #pragma unroll
            for (int t = 0; t < 4; ++t) {
                const float4* ps = (const float4*)(xf + (long)sidx[t] * LAT);
                const float4* pt = (const float4*)(xf + (long)tidx[t] * LAT);
                float4 sa = ps[2 * g], sb = ps[2 * g + 1], sc = ps[8 + 2 * g], sd = ps[9 + 2 * g];
                float4 ta = pt[2 * g], tb = pt[2 * g + 1], tc = pt[8 + 2 * g], td = pt[9 + 2 * g];
                MnMx4 m0 = mnmx4(sa, ta);
                MnMx4 m1 = mnmx4(sb, tb);
                MnMx4 m2 = mnmx4(sc, tc);
                MnMx4 m3 = mnmx4(sd, td);
                union { short8 s; u32x4 u; } af0, af1, af2, af3;
                af0.u[0] = m0.w0; af0.u[1] = m0.w1; af2.u[0] = m0.x0; af2.u[1] = m0.x1;
                af0.u[2] = m1.w0; af0.u[3] = m1.w1; af2.u[2] = m1.x0; af2.u[3] = m1.x1;
                af1.u[0] = m2.w0; af1.u[1] = m2.w1; af3.u[0] = m2.x0; af3.u[1] = m2.x1;
                af1.u[2] = m3.w0; af1.u[3] = m3.w1; af3.u[2] = m3.x0; af3.u[3] = m3.x1;
                mfma_core(af0.s, af1.s, af2.s, af3.s, ebase + t * 16 + r);
            }
        }
    }
}

// ---------- fallback (tiny ws): per-thread fp32 kernel ----------
__global__ __launch_bounds__(256) void edge_pred_fp32_kernel(
    const float* __restrict__ x, const int* __restrict__ ei,
    const float* __restrict__ Wd, const float* __restrict__ bd,
    const float* __restrict__ W1, const float* __restrict__ b1,
    const float* __restrict__ W2, const float* __restrict__ b2,
    const float* __restrict__ W3, const float* __restrict__ b3,
    float* __restrict__ out, int E)
{
    int e = blockIdx.x * blockDim.x + threadIdx.x;
    if (e >= E) return;
    int s = ei[e];
    int t = ei[E + e];
    const float4* xs4 = (const float4*)(x + (long)s * 64);
    const float4* xt4 = (const float4*)(x + (long)t * 64);
    float h[HID];
    #pragma unroll
    for (int j = 0; j < HID; ++j) h[j] = b1[j];
    float d0 = bd[0], d1 = bd[1], d2 = bd[2], d3 = bd[3];
    #pragma unroll 2
    for (int c = 0; c < 16; ++c) {
        float4 a = xs4[c];
        float4 b = xt4[c];
        float mn[4] = {fminf(a.x,b.x), fminf(a.y,b.y), fminf(a.z,b.z), fminf(a.w,b.w)};
        float mx[4] = {fmaxf(a.x,b.x), fmaxf(a.y,b.y), fmaxf(a.z,b.z), fmaxf(a.w,b.w)};
        #pragma unroll
        for (int q = 0; q < 4; ++q) {
            int lidx = c * 4 + q;
            const float* wlo = W1 + lidx * HID;
            const float* whi = W1 + (64 + lidx) * HID;
            #pragma unroll
            for (int j = 0; j < HID; ++j) { h[j] += mn[q]*wlo[j]; h[j] += mx[q]*whi[j]; }
            const float* dlo = Wd + lidx * 4;
            const float* dhi = Wd + (64 + lidx) * 4;
            d0 += mn[q]*dlo[0] + mx[q]*dhi[0];
            d1 += mn[q]*dlo[1] + mx[q]*dhi[1];
            d2 += mn[q]*dlo[2] + mx[q]*dhi[2];
            d3 += mn[q]*dlo[3] + mx[q]*dhi[3];
        }
    }
    float h1[HID];
    #pragma unroll
    for (int j = 0; j < HID; ++j) h1[j] = fmaxf(h[j], 0.0f);
    float s2[HID];
    #pragma unroll
    for (int j = 0; j < HID; ++j) s2[j] = b2[j] + h1[j];
    #pragma unroll 4
    for (int k = 0; k < HID; ++k) {
        const float* w2r = W2 + k * HID;
        #pragma unroll
        for (int j = 0; j < HID; ++j) s2[j] += h1[k] * w2r[j];
    }
    float o0 = b3[0] + d0, o1 = b3[1] + d1, o2 = b3[2] + d2, o3 = b3[3] + d3;
    #pragma unroll
    for (int k = 0; k < HID; ++k) {
        float hk = fmaxf(s2[k], 0.0f);
        const float* w3r = W3 + k * 4;
        o0 += hk*w3r[0]; o1 += hk*w3r[1]; o2 += hk*w3r[2]; o3 += hk*w3r[3];
    }
    *(float4*)(out + (long)e * 4) = make_float4(o0, o1, o2, o3);
}

extern "C" void kernel_launch(void* const* d_in, const int* in_sizes, int n_in,
                              void* d_out, int out_size, void* d_ws, size_t ws_size,
                              hipStream_t stream) {
    const float* x  = (const float*)d_in[0];
    const int*   ei = (const int*)d_in[1];
    const float* Wd = (const float*)d_in[2];
    const float* bd = (const float*)d_in[3];
    const float* W1 = (const float*)d_in[4];
    const float* b1 = (const float*)d_in[5];
    const float* W2 = (const float*)d_in[6];
    const float* b2 = (const float*)d_in[7];
    const float* W3 = (const float*)d_in[8];
    const float* b3 = (const float*)d_in[9];
    float* out = (float*)d_out;

    int E  = in_sizes[1] / 2;
    int NN = in_sizes[0] / LAT;
    int nch = (E + EPB - 1) / EPB;

    size_t fbytes  = (size_t)NFRAG  * 64 * 16;   // 12 KB W1aug frags
    size_t f2bytes = (size_t)NFRAG2 * 64 * 16;   // 2 KB  W2aug frags
    size_t f3bytes = (size_t)NFRAG3 * 64 * 16;   // 1 KB  W3aug frag
    size_t fall    = fbytes + f2bytes + f3bytes;
    size_t fpad    = (fall + 255) & ~(size_t)255;
    size_t xbytes  = (size_t)NN * LAT * 2;       // bf16 x

    int grid = (nch < 1024) ? nch : 1024;        // persistent: ~4 blocks/CU resident
    if (ws_size >= fpad + xbytes) {
        unsigned short* frg  = (unsigned short*)d_ws;
        unsigned short* frg2 = (unsigned short*)((char*)d_ws + fbytes);
        unsigned short* frg3 = (unsigned short*)((char*)d_ws + fbytes + f2bytes);
        unsigned short* xb   = (unsigned short*)((char*)d_ws + fpad);
        int n8 = NN * LAT / 8;
        int prep_grid = 4 + (n8 + 255) / 256;
        hipLaunchKernelGGL(prep_kernel, dim3(prep_grid), dim3(256), 0, stream,
                           x, W1, Wd, W2, W3, frg, frg2, frg3, xb, n8);
        hipLaunchKernelGGL((edge_mfma_kernel<1>), dim3(grid), dim3(256), 0, stream,
                           x, xb, frg, ei, b1, bd, b2, b3, out, E, nch);
    } else if (ws_size >= fall) {
        unsigned short* frg  = (unsigned short*)d_ws;
        unsigned short* frg2 = (unsigned short*)((char*)d_ws + fbytes);
        unsigned short* frg3 = (unsigned short*)((char*)d_ws + fbytes + f2bytes);
        hipLaunchKernelGGL(prep_kernel, dim3(4), dim3(256), 0, stream,
                           x, W1, Wd, W2, W3, frg, frg2, frg3,
                           (unsigned short*)nullptr, 0);
        hipLaunchKernelGGL((edge_mfma_kernel<0>), dim3(grid), dim3(256), 0, stream,
                           x, (const unsigned short*)nullptr, frg,
                           ei, b1, bd, b2, b3, out, E, nch);
    } else {
        hipLaunchKernelGGL(edge_pred_fp32_kernel, dim3((E + 255) / 256), dim3(256), 0, stream,
                           x, ei, Wd, bd, W1, b1, W2, b2, W3, b3, out, E);
    }
}